// Round 4
// baseline (120.589 us; speedup 1.0000x reference)
//
#include <hip/hip_runtime.h>

// Deformable conv (K=3, stride=1, pad=1, dil=1), N=8, Cin=Cout=128, H=W=64.
// v5: - occupancy attack: grid 1024 (block = 32 wo x 128 co, 256 thr / 4 waves,
//       wave tile 32x32). samp LDS 17.4KB, VGPR ~104 -> 4 independent blocks/CU
//       (16 waves/CU, 4 barrier groups) vs v4's 2. Latency now hidden by TLP.
//     - weight regs single-buffered: bW reloaded in place AFTER the MFMA phase
//       (sched_barrier fence); loads land during blend+barrier. Saves 32 VGPR.
//     - s_setprio(1) around MFMA cluster (independent-block structure = the case
//       where it measured +4-7%).
//     - keeps v4's wins: XCD-local n=bid&7 (FETCH 41.6->6.5MB), reg B-frags,
//       v_cvt_pk_bf16_f32, 1 barrier/kk.
// ws usage: xt = 8 MB at ws+0, wt = 288 KB at ws+8388608. Fully rewritten each launch.

#define H  64
#define W  64
#define CIN 128
#define COUT 128
#define NB 8
#define KK 9
#define SROW (CIN + 8)

typedef short bf16x8 __attribute__((ext_vector_type(8)));
typedef float f32x4  __attribute__((ext_vector_type(4)));

__device__ __forceinline__ unsigned short f2bf(float f) {
    unsigned u = __builtin_bit_cast(unsigned, f);
    u += 0x7FFFu + ((u >> 16) & 1u);          // round-nearest-even
    return (unsigned short)(u >> 16);
}
__device__ __forceinline__ unsigned cvt_pk_bf16(float lo, float hi) {
    unsigned r;
    asm("v_cvt_pk_bf16_f32 %0, %1, %2" : "=v"(r) : "v"(lo), "v"(hi));
    return r;                                  // low16 = bf16(lo), high16 = bf16(hi), RNE
}
__device__ __forceinline__ float lo_f(unsigned u) { return __builtin_bit_cast(float, u << 16); }
__device__ __forceinline__ float hi_f(unsigned u) { return __builtin_bit_cast(float, u & 0xFFFF0000u); }

// Merged prep: blocks [0, NB*H) transpose x (NCHW fp32 -> NHWC bf16), XCD-local (n = b&7);
// blocks [NB*H, NB*H+576) convert weight fp32 [co][c][kk] -> bf16 [kk][co][c].
__global__ void prep_all(const float* __restrict__ x, const float* __restrict__ w,
                         unsigned short* __restrict__ xt, unsigned short* __restrict__ wt) {
    int b = blockIdx.x;
    int t = threadIdx.x;
    if (b >= NB * H) {                        // ---- weight part ----
        int idx = (b - NB * H) * 256 + t;
        if (idx < KK * COUT * CIN) {
            int kk = idx / (COUT * CIN);
            int r  = idx - kk * (COUT * CIN);
            int co = r >> 7;
            int c  = r & 127;
            wt[idx] = f2bf(w[(co * CIN + c) * KK + kk]);
        }
        return;
    }
    // ---- x-transpose part: one (n,y) row per block; n = b&7 matches deform's XCD map ----
    __shared__ float tile[CIN][W + 4];
    int n = b & 7, y = b >> 3;
    const float* src = x + ((size_t)n * CIN * H + y) * W;
    #pragma unroll
    for (int it = 0; it < 8; ++it) {
        int idx = it * 256 + t;               // 0..2047 float4s
        int c  = idx >> 4;
        int x4 = (idx & 15) << 2;
        int xs = (x4 + ((c >> 5) << 4)) & 63; // rotate-swizzle per 32-ch group
        *(float4*)&tile[c][xs] = *(const float4*)(src + (size_t)c * H * W + x4);
    }
    __syncthreads();
    int xp = t >> 2;                          // x position 0..63
    int cbch = (t & 3) << 5;                  // channel base (32-ch chunk)
    int xr = (xp + ((cbch >> 5) << 4)) & 63;
    unsigned short* dst = xt + (((size_t)(n * H + y) * W + xp) * CIN + cbch);
    unsigned rr[16];
    #pragma unroll
    for (int i = 0; i < 16; ++i)
        rr[i] = cvt_pk_bf16(tile[cbch + 2 * i][xr], tile[cbch + 2 * i + 1][xr]);
    #pragma unroll
    for (int i = 0; i < 4; ++i)
        ((uint4*)dst)[i] = make_uint4(rr[4*i], rr[4*i+1], rr[4*i+2], rr[4*i+3]);
}

struct GatherCtx {
    const unsigned short *c00, *c01, *c10, *c11;
    float w00, w01, w10, w11;
};

__device__ __forceinline__ GatherCtx gather_setup(float dy, float dx, int ho, int wo, int kk,
                                                  const unsigned short* xbase) {
    GatherCtx g;
    float py = (float)(ho - 1 + kk / 3) + dy;
    float px = (float)(wo - 1 + kk % 3) + dx;
    float y0f = floorf(py), x0f = floorf(px);
    float wy1 = py - y0f, wx1 = px - x0f;
    float wy0 = 1.f - wy1, wx0 = 1.f - wx1;
    int y0 = (int)y0f, x0 = (int)x0f;
    int y1 = y0 + 1, x1 = x0 + 1;
    bool vy0 = (unsigned)y0 < (unsigned)H, vy1 = (unsigned)y1 < (unsigned)H;
    bool vx0 = (unsigned)x0 < (unsigned)W, vx1 = (unsigned)x1 < (unsigned)W;
    g.w00 = (vy0 && vx0) ? wy0 * wx0 : 0.f;
    g.w01 = (vy0 && vx1) ? wy0 * wx1 : 0.f;
    g.w10 = (vy1 && vx0) ? wy1 * wx0 : 0.f;
    g.w11 = (vy1 && vx1) ? wy1 * wx1 : 0.f;
    int yc0 = min(max(y0, 0), H - 1), yc1 = min(max(y1, 0), H - 1);
    int xc0 = min(max(x0, 0), W - 1), xc1 = min(max(x1, 0), W - 1);
    const unsigned short* r0 = xbase + (size_t)yc0 * W * CIN;
    const unsigned short* r1 = xbase + (size_t)yc1 * W * CIN;
    g.c00 = r0 + xc0 * CIN;  g.c01 = r0 + xc1 * CIN;
    g.c10 = r1 + xc0 * CIN;  g.c11 = r1 + xc1 * CIN;
    return g;
}

// 16 channels per thread: 2 x b128 per corner, grouped per 8-ch chunk j.
__device__ __forceinline__ void gather_issue(const GatherCtx& g, uint4* gv) {
    #pragma unroll
    for (int j = 0; j < 2; ++j) {
        gv[4*j+0] = *(const uint4*)(g.c00 + 8*j);
        gv[4*j+1] = *(const uint4*)(g.c01 + 8*j);
        gv[4*j+2] = *(const uint4*)(g.c10 + 8*j);
        gv[4*j+3] = *(const uint4*)(g.c11 + 8*j);
    }
}

__device__ __forceinline__ void gather_blend_store(const GatherCtx& g, const uint4* gv,
                                                   unsigned short* dst) {
    #pragma unroll
    for (int j = 0; j < 2; ++j) {
        const unsigned* a0 = (const unsigned*)&gv[4*j+0];
        const unsigned* a1 = (const unsigned*)&gv[4*j+1];
        const unsigned* a2 = (const unsigned*)&gv[4*j+2];
        const unsigned* a3 = (const unsigned*)&gv[4*j+3];
        unsigned rr[4];
        #pragma unroll
        for (int i = 0; i < 4; ++i) {
            float v0 = g.w00*lo_f(a0[i]) + g.w01*lo_f(a1[i]) + g.w10*lo_f(a2[i]) + g.w11*lo_f(a3[i]);
            float v1 = g.w00*hi_f(a0[i]) + g.w01*hi_f(a1[i]) + g.w10*hi_f(a2[i]) + g.w11*hi_f(a3[i]);
            rr[i] = cvt_pk_bf16(v0, v1);
        }
        *(uint4*)(dst + 8*j) = make_uint4(rr[0], rr[1], rr[2], rr[3]);
    }
}

// Load this wave's B-fragments for kernel-tap kkv into the (single) register bank.
#define LOADB(kkv) { \
    const unsigned short* wk_ = wlane + ((size_t)(kkv) << 14); /* kk*COUT*CIN */ \
    _Pragma("unroll") \
    for (int nt_ = 0; nt_ < 2; ++nt_) \
        _Pragma("unroll") \
        for (int ct_ = 0; ct_ < 4; ++ct_) \
            bW[nt_][ct_] = *(const bf16x8*)(wk_ + (nt_ << 11) + (ct_ << 5)); }

#define MFMA_PHASE(PAR) { \
    __builtin_amdgcn_s_setprio(1); \
    _Pragma("unroll") \
    for (int ct_ = 0; ct_ < 4; ++ct_) { \
        bf16x8 a_[2]; \
        _Pragma("unroll") \
        for (int mt_ = 0; mt_ < 2; ++mt_) \
            a_[mt_] = *(const bf16x8*)&samp[PAR][lm + (mt_ << 4)][(ct_ << 5) + (lq << 3)]; \
        _Pragma("unroll") \
        for (int mt_ = 0; mt_ < 2; ++mt_) { \
            acc[mt_][0] = __builtin_amdgcn_mfma_f32_16x16x32_bf16(a_[mt_], bW[0][ct_], acc[mt_][0], 0, 0, 0); \
            acc[mt_][1] = __builtin_amdgcn_mfma_f32_16x16x32_bf16(a_[mt_], bW[1][ct_], acc[mt_][1], 0, 0, 0); } } \
    __builtin_amdgcn_s_setprio(0); }

// One iteration: issue kk+1 gathers (pinned above MFMA), MFMA(kk) from bW,
// reload bW with kk+1 (in place, WAR-safe; lands during blend+barrier),
// blend+write samp[(kk+1)&1], barrier.
#define ITER(kkv, PAR, LAST) { \
    GatherCtx g_; uint4 gv_[8]; \
    if (!(LAST)) { \
        g_ = gather_setup(dyA, dxA, ho, wo_g, (kkv) + 1, xbase); \
        gather_issue(g_, gv_); \
        if ((kkv) < KK - 2) { \
            dyA = offbase[(size_t)(2 * ((kkv) + 2)) * H * W]; \
            dxA = offbase[(size_t)(2 * ((kkv) + 2) + 1) * H * W]; \
        } \
    } \
    __builtin_amdgcn_sched_barrier(0); /* keep gather issue above the MFMAs */ \
    MFMA_PHASE(PAR); \
    __builtin_amdgcn_sched_barrier(0); /* keep bW reload below the MFMAs */ \
    if (!(LAST)) { \
        LOADB((kkv) + 1); \
        gather_blend_store(g_, gv_, &samp[1 - (PAR)][p][cb]); \
        __syncthreads(); \
    } }

// One block per (n, ho, wo-half): n = bid&7 (XCD-local), ho = (bid>>3)&63, hf = bid>>9.
// 256 threads = 4 waves. Wave wv: 32 wo x couts wv*32..+31 (2 m-subtiles x 2 n-subtiles).
__global__ __launch_bounds__(256, 4) void deform_main(
        const float* __restrict__ offs, const unsigned short* __restrict__ xt,
        const unsigned short* __restrict__ wt, float* __restrict__ out) {
    // +8 bf16 pad per row -> row stride 272B (68 words == 4 mod 32): uniform bank use on b128
    __shared__ __attribute__((aligned(16))) unsigned short samp[2][32][SROW];  // 17,408 B

    int b = blockIdx.x;
    int n = b & 7, ho = (b >> 3) & 63, hf = b >> 9;
    int t = threadIdx.x;
    int lane = t & 63, wv = t >> 6;
    int lm = lane & 15, lq = lane >> 4;
    int cobase = wv << 5;

    f32x4 acc[2][2];
    #pragma unroll
    for (int mt = 0; mt < 2; ++mt)
        #pragma unroll
        for (int nt = 0; nt < 2; ++nt) acc[mt][nt] = f32x4{0.f, 0.f, 0.f, 0.f};

    // sampling map: thread -> (local position p in 0..31, 16-channel chunk cb)
    int p  = t >> 3;
    int cb = (t & 7) << 4;
    int wo_g = (hf << 5) + p;               // global wo this thread samples
    const float* offbase = offs + (size_t)n * 2 * KK * H * W + (size_t)ho * W + wo_g;
    const unsigned short* xbase = xt + (size_t)n * H * W * CIN + cb;
    // per-lane B-fragment base: frag(kk,nt,ct) at wt[(kk*COUT + cobase + nt*16 + lm)*CIN + ct*32 + lq*8]
    const unsigned short* wlane = wt + (((size_t)(cobase + lm)) << 7) + (lq << 3);

    bf16x8 bW[2][4];                        // single-buffered B-fragment bank

    // ---- prologue: gather kk=0 + B0; write samp[0]; barrier ----
    float dyA = offbase[0];
    float dxA = offbase[(size_t)H * W];
    {
        GatherCtx g = gather_setup(dyA, dxA, ho, wo_g, 0, xbase);
        uint4 gv[8];
        gather_issue(g, gv);
        LOADB(0);
        dyA = offbase[(size_t)2 * H * W];
        dxA = offbase[(size_t)3 * H * W];
        gather_blend_store(g, gv, &samp[0][p][cb]);
        __syncthreads();
    }

    for (int k2 = 0; k2 < 4; ++k2) {
        ITER(2 * k2,     0, false);
        ITER(2 * k2 + 1, 1, false);
    }
    ITER(8, 0, true);

    // epilogue: D[m = mt*16 + lq*4 + j][n = lm] -> out[n][co][ho][wo], float4 over wo
    #pragma unroll
    for (int mt = 0; mt < 2; ++mt) {
        int wob = (hf << 5) + (mt << 4) + (lq << 2);
        #pragma unroll
        for (int nt = 0; nt < 2; ++nt) {
            int co = cobase + (nt << 4) + lm;
            *(f32x4*)(out + (((size_t)(n * COUT + co) * H + ho) * W + wob)) = acc[mt][nt];
        }
    }
}

extern "C" void kernel_launch(void* const* d_in, const int* in_sizes, int n_in,
                              void* d_out, int out_size, void* d_ws, size_t ws_size,
                              hipStream_t stream) {
    const float* x      = (const float*)d_in[0];   // (8,128,64,64)
    const float* offset = (const float*)d_in[1];   // (8,18,64,64)
    const float* weight = (const float*)d_in[2];   // (128,128,3,3)
    float* out = (float*)d_out;

    unsigned short* xt = (unsigned short*)d_ws;                                  // 8 MB
    unsigned short* wt = (unsigned short*)((char*)d_ws + (size_t)NB*H*W*CIN*2);  // 288 KB

    int wblocks = (KK * COUT * CIN + 255) / 256;   // 576
    hipLaunchKernelGGL(prep_all, dim3(NB * H + wblocks), dim3(256), 0, stream,
                       x, weight, xt, wt);
    hipLaunchKernelGGL(deform_main, dim3(NB * H * 2), dim3(256), 0, stream,
                       offset, xt, wt, out);
}

// Round 5
// 119.366 us; speedup vs baseline: 1.0102x; 1.0102x over previous
//
#include <hip/hip_runtime.h>

// Deformable conv (K=3, stride=1, pad=1, dil=1), N=8, Cin=Cout=128, H=W=64.
// v6: - rounds 1/3/4 proved hipcc SINKS C++-level prefetch loads past the MFMA phase
//       (VGPR 60 both times) regardless of sched_barrier. Fix: all staging loads are
//       inline-asm global_load_dwordx4 with "=v" outputs (unsinkable, un-rematerializable),
//       manual s_waitcnt vmcnt(0) + sched_barrier(0) before the consumers (rule #18).
//     - v4 geometry (better measured than v5): grid 512 (n=bid&7 XCD-local, ho=bid>>3),
//       256 thr / 4 waves, wave 64wo x 32co (4 mt x 2 nt x 4 ct = 32 MFMA/kk).
//     - B-fragments: double-buffered asm-loaded register banks (2 x 32 VGPR), no LDS.
//     - samp double-buffered in LDS (69.6KB), 1 barrier/kk; 2 blocks/CU.
// ws usage: xt = 8 MB at ws+0, wt = 288 KB at ws+8388608. Fully rewritten each launch.

#define H  64
#define W  64
#define CIN 128
#define COUT 128
#define NB 8
#define KK 9
#define SROW (CIN + 8)

typedef short bf16x8 __attribute__((ext_vector_type(8)));
typedef float f32x4  __attribute__((ext_vector_type(4)));

// unsinkable 16B global load into explicit VGPRs
#define GLOADX4(dst, ptr) \
    asm volatile("global_load_dwordx4 %0, %1, off" : "=v"(dst) : "v"(ptr))
// drain all asm loads, then fence so consumers can't be hoisted above (rule #18)
#define WAITVM0() { asm volatile("s_waitcnt vmcnt(0)" ::: "memory"); \
                    __builtin_amdgcn_sched_barrier(0); }

__device__ __forceinline__ unsigned short f2bf(float f) {
    unsigned u = __builtin_bit_cast(unsigned, f);
    u += 0x7FFFu + ((u >> 16) & 1u);          // round-nearest-even
    return (unsigned short)(u >> 16);
}
__device__ __forceinline__ unsigned cvt_pk_bf16(float lo, float hi) {
    unsigned r;
    asm("v_cvt_pk_bf16_f32 %0, %1, %2" : "=v"(r) : "v"(lo), "v"(hi));
    return r;                                  // low16 = bf16(lo), high16 = bf16(hi), RNE
}
__device__ __forceinline__ float lo_f(unsigned u) { return __builtin_bit_cast(float, u << 16); }
__device__ __forceinline__ float hi_f(unsigned u) { return __builtin_bit_cast(float, u & 0xFFFF0000u); }

// Merged prep: blocks [0, NB*H) transpose x (NCHW fp32 -> NHWC bf16), XCD-local (n = b&7);
// blocks [NB*H, NB*H+576) convert weight fp32 [co][c][kk] -> bf16 [kk][co][c].
__global__ void prep_all(const float* __restrict__ x, const float* __restrict__ w,
                         unsigned short* __restrict__ xt, unsigned short* __restrict__ wt) {
    int b = blockIdx.x;
    int t = threadIdx.x;
    if (b >= NB * H) {                        // ---- weight part ----
        int idx = (b - NB * H) * 256 + t;
        if (idx < KK * COUT * CIN) {
            int kk = idx / (COUT * CIN);
            int r  = idx - kk * (COUT * CIN);
            int co = r >> 7;
            int c  = r & 127;
            wt[idx] = f2bf(w[(co * CIN + c) * KK + kk]);
        }
        return;
    }
    // ---- x-transpose part: one (n,y) row per block; n = b&7 matches deform's XCD map ----
    __shared__ float tile[CIN][W + 4];
    int n = b & 7, y = b >> 3;
    const float* src = x + ((size_t)n * CIN * H + y) * W;
    #pragma unroll
    for (int it = 0; it < 8; ++it) {
        int idx = it * 256 + t;               // 0..2047 float4s
        int c  = idx >> 4;
        int x4 = (idx & 15) << 2;
        int xs = (x4 + ((c >> 5) << 4)) & 63; // rotate-swizzle per 32-ch group
        *(float4*)&tile[c][xs] = *(const float4*)(src + (size_t)c * H * W + x4);
    }
    __syncthreads();
    int xp = t >> 2;                          // x position 0..63
    int cbch = (t & 3) << 5;                  // channel base (32-ch chunk)
    int xr = (xp + ((cbch >> 5) << 4)) & 63;
    unsigned short* dst = xt + (((size_t)(n * H + y) * W + xp) * CIN + cbch);
    unsigned rr[16];
    #pragma unroll
    for (int i = 0; i < 16; ++i)
        rr[i] = cvt_pk_bf16(tile[cbch + 2 * i][xr], tile[cbch + 2 * i + 1][xr]);
    #pragma unroll
    for (int i = 0; i < 4; ++i)
        ((uint4*)dst)[i] = make_uint4(rr[4*i], rr[4*i+1], rr[4*i+2], rr[4*i+3]);
}

struct GatherCtx {
    const unsigned short *c00, *c01, *c10, *c11;
    float w00, w01, w10, w11;
};

__device__ __forceinline__ GatherCtx gather_setup(float dy, float dx, int ho, int wo, int kk,
                                                  const unsigned short* xbase) {
    GatherCtx g;
    float py = (float)(ho - 1 + kk / 3) + dy;
    float px = (float)(wo - 1 + kk % 3) + dx;
    float y0f = floorf(py), x0f = floorf(px);
    float wy1 = py - y0f, wx1 = px - x0f;
    float wy0 = 1.f - wy1, wx0 = 1.f - wx1;
    int y0 = (int)y0f, x0 = (int)x0f;
    int y1 = y0 + 1, x1 = x0 + 1;
    bool vy0 = (unsigned)y0 < (unsigned)H, vy1 = (unsigned)y1 < (unsigned)H;
    bool vx0 = (unsigned)x0 < (unsigned)W, vx1 = (unsigned)x1 < (unsigned)W;
    g.w00 = (vy0 && vx0) ? wy0 * wx0 : 0.f;
    g.w01 = (vy0 && vx1) ? wy0 * wx1 : 0.f;
    g.w10 = (vy1 && vx0) ? wy1 * wx0 : 0.f;
    g.w11 = (vy1 && vx1) ? wy1 * wx1 : 0.f;
    int yc0 = min(max(y0, 0), H - 1), yc1 = min(max(y1, 0), H - 1);
    int xc0 = min(max(x0, 0), W - 1), xc1 = min(max(x1, 0), W - 1);
    const unsigned short* r0 = xbase + (size_t)yc0 * W * CIN;
    const unsigned short* r1 = xbase + (size_t)yc1 * W * CIN;
    g.c00 = r0 + xc0 * CIN;  g.c01 = r0 + xc1 * CIN;
    g.c10 = r1 + xc0 * CIN;  g.c11 = r1 + xc1 * CIN;
    return g;
}

// 32 channels per thread: 4 x b128 per corner, all 16 loads issued via asm (unsinkable).
__device__ __forceinline__ void gather_issue_asm(const GatherCtx& g, uint4* gv) {
    #pragma unroll
    for (int j = 0; j < 4; ++j) {
        GLOADX4(gv[4*j+0], g.c00 + 8*j);
        GLOADX4(gv[4*j+1], g.c01 + 8*j);
        GLOADX4(gv[4*j+2], g.c10 + 8*j);
        GLOADX4(gv[4*j+3], g.c11 + 8*j);
    }
}

__device__ __forceinline__ void gather_blend_store(const GatherCtx& g, const uint4* gv,
                                                   unsigned short* dst) {
    #pragma unroll
    for (int j = 0; j < 4; ++j) {
        const unsigned* a0 = (const unsigned*)&gv[4*j+0];
        const unsigned* a1 = (const unsigned*)&gv[4*j+1];
        const unsigned* a2 = (const unsigned*)&gv[4*j+2];
        const unsigned* a3 = (const unsigned*)&gv[4*j+3];
        unsigned rr[4];
        #pragma unroll
        for (int i = 0; i < 4; ++i) {
            float v0 = g.w00*lo_f(a0[i]) + g.w01*lo_f(a1[i]) + g.w10*lo_f(a2[i]) + g.w11*lo_f(a3[i]);
            float v1 = g.w00*hi_f(a0[i]) + g.w01*hi_f(a1[i]) + g.w10*hi_f(a2[i]) + g.w11*hi_f(a3[i]);
            rr[i] = cvt_pk_bf16(v0, v1);
        }
        *(uint4*)(dst + 8*j) = make_uint4(rr[0], rr[1], rr[2], rr[3]);
    }
}

// asm-load this wave's 8 B-fragments for kernel-tap kkv into register bank `bank`.
#define LOADB_ASM(bank, kkv) { \
    const unsigned short* wk_ = wlane + ((size_t)(kkv) << 14); /* kk*COUT*CIN */ \
    _Pragma("unroll") \
    for (int nt_ = 0; nt_ < 2; ++nt_) \
        _Pragma("unroll") \
        for (int ct_ = 0; ct_ < 4; ++ct_) \
            GLOADX4(bank[nt_][ct_], (wk_ + (nt_ << 11) + (ct_ << 5))); }

#define MFMA_PHASE(PAR, BREG) { \
    __builtin_amdgcn_s_setprio(1); \
    _Pragma("unroll") \
    for (int ct_ = 0; ct_ < 4; ++ct_) { \
        bf16x8 a_[4]; \
        _Pragma("unroll") \
        for (int mt_ = 0; mt_ < 4; ++mt_) \
            a_[mt_] = *(const bf16x8*)&samp[PAR][lm + (mt_ << 4)][(ct_ << 5) + (lq << 3)]; \
        _Pragma("unroll") \
        for (int mt_ = 0; mt_ < 4; ++mt_) { \
            acc[mt_][0] = __builtin_amdgcn_mfma_f32_16x16x32_bf16(a_[mt_], BREG[0][ct_], acc[mt_][0], 0, 0, 0); \
            acc[mt_][1] = __builtin_amdgcn_mfma_f32_16x16x32_bf16(a_[mt_], BREG[1][ct_], acc[mt_][1], 0, 0, 0); } } \
    __builtin_amdgcn_s_setprio(0); }

// One iteration: asm-issue kk+1 gathers + B(kk+1) into BNXT, MFMA(kk) from BCUR,
// drain vmcnt, blend+write samp[1-PAR], barrier. All loads pinned by asm.
#define ITER(kkv, PAR, BCUR, BNXT, LAST) { \
    GatherCtx g_; uint4 gv_[16]; \
    if (!(LAST)) { \
        g_ = gather_setup(dyA, dxA, ho, p, (kkv) + 1, xbase); \
        gather_issue_asm(g_, gv_); \
        LOADB_ASM(BNXT, (kkv) + 1); \
        if ((kkv) < KK - 2) { \
            dyA = offbase[(size_t)(2 * ((kkv) + 2)) * H * W]; \
            dxA = offbase[(size_t)(2 * ((kkv) + 2) + 1) * H * W]; \
        } \
    } \
    __builtin_amdgcn_sched_barrier(0); \
    MFMA_PHASE(PAR, BCUR); \
    __builtin_amdgcn_sched_barrier(0); \
    if (!(LAST)) { \
        WAITVM0(); \
        gather_blend_store(g_, gv_, &samp[1 - (PAR)][p][cb]); \
        __syncthreads(); \
    } }

// One block per (n, ho); n = bid&7 (XCD-local), ho = bid>>3. 256 threads = 4 waves.
// Wave wv: all 64 wo x couts wv*32..+31 (4 m-subtiles x 2 n-subtiles of 16x16x32).
__global__ __launch_bounds__(256, 2) void deform_main(
        const float* __restrict__ offs, const unsigned short* __restrict__ xt,
        const unsigned short* __restrict__ wt, float* __restrict__ out) {
    // +8 bf16 pad per row -> row stride 272B (68 words == 4 mod 32): uniform bank use on b128
    __shared__ __attribute__((aligned(16))) unsigned short samp[2][64][SROW];  // 69,632 B

    int b = blockIdx.x;
    int n = b & 7, ho = b >> 3;
    int t = threadIdx.x;
    int lane = t & 63, wv = t >> 6;
    int lm = lane & 15, lq = lane >> 4;
    int cobase = wv << 5;

    f32x4 acc[4][2];
    #pragma unroll
    for (int mt = 0; mt < 4; ++mt)
        #pragma unroll
        for (int nt = 0; nt < 2; ++nt) acc[mt][nt] = f32x4{0.f, 0.f, 0.f, 0.f};

    // sampling map: thread -> (position p = wo in 0..63, 32-channel chunk cb)
    int p  = t >> 2;
    int cb = (t & 3) << 5;
    const float* offbase = offs + (size_t)n * 2 * KK * H * W + (size_t)ho * W + p;
    const unsigned short* xbase = xt + (size_t)n * H * W * CIN + cb;
    // per-lane B-fragment base: frag(kk,nt,ct) at wt[(kk*COUT + cobase + nt*16 + lm)*CIN + ct*32 + lq*8]
    const unsigned short* wlane = wt + (((size_t)(cobase + lm)) << 7) + (lq << 3);

    bf16x8 bA[2][4], bB[2][4];   // double-buffered asm-loaded B-fragment banks

    // ---- prologue: asm-gather kk=0 + B0 into bA; drain; write samp[0]; barrier ----
    float dyA = offbase[0];
    float dxA = offbase[(size_t)H * W];
    {
        GatherCtx g = gather_setup(dyA, dxA, ho, p, 0, xbase);
        uint4 gv[16];
        gather_issue_asm(g, gv);
        LOADB_ASM(bA, 0);
        dyA = offbase[(size_t)2 * H * W];
        dxA = offbase[(size_t)3 * H * W];
        WAITVM0();
        gather_blend_store(g, gv, &samp[0][p][cb]);
        __syncthreads();
    }

    for (int k2 = 0; k2 < 4; ++k2) {
        ITER(2 * k2,     0, bA, bB, false);
        ITER(2 * k2 + 1, 1, bB, bA, false);
    }
    ITER(8, 0, bA, bB, true);

    // epilogue: D[m = mt*16 + lq*4 + j][n = lm] -> out[n][co][ho][wo], float4 over wo
    #pragma unroll
    for (int mt = 0; mt < 4; ++mt) {
        int wob = (mt << 4) + (lq << 2);
        #pragma unroll
        for (int nt = 0; nt < 2; ++nt) {
            int co = cobase + (nt << 4) + lm;
            *(f32x4*)(out + (((size_t)(n * COUT + co) * H + ho) * W + wob)) = acc[mt][nt];
        }
    }
}

extern "C" void kernel_launch(void* const* d_in, const int* in_sizes, int n_in,
                              void* d_out, int out_size, void* d_ws, size_t ws_size,
                              hipStream_t stream) {
    const float* x      = (const float*)d_in[0];   // (8,128,64,64)
    const float* offset = (const float*)d_in[1];   // (8,18,64,64)
    const float* weight = (const float*)d_in[2];   // (128,128,3,3)
    float* out = (float*)d_out;

    unsigned short* xt = (unsigned short*)d_ws;                                  // 8 MB
    unsigned short* wt = (unsigned short*)((char*)d_ws + (size_t)NB*H*W*CIN*2);  // 288 KB

    int wblocks = (KK * COUT * CIN + 255) / 256;   // 576
    hipLaunchKernelGGL(prep_all, dim3(NB * H + wblocks), dim3(256), 0, stream,
                       x, weight, xt, wt);
    hipLaunchKernelGGL(deform_main, dim3(NB * H), dim3(256), 0, stream,
                       offset, xt, wt, out);
}

// Round 6
// 111.030 us; speedup vs baseline: 1.0861x; 1.0751x over previous
//
#include <hip/hip_runtime.h>

// Deformable conv (K=3, stride=1, pad=1, dil=1), N=8, Cin=Cout=128, H=W=64.
// v7: producer/consumer wave specialization.
//   Evidence: v0/v3/v4/v5/v6 all land 40-50us regardless of structure; v6 counters
//   show ~32us/CU of pipe-busy (TA ~11 + VALU ~10 + LDS ~7 + MFMA ~3.6) executing
//   SERIALLY because every wave runs the same {issue->MFMA->wait->blend->barrier}
//   chain and resident blocks are phase-locked clones. Fix = overlap pipes across
//   waves, not within a wave:
//   - 512-thr block (8 waves), grid 512 -> 16 waves/CU (2 blocks).
//   - waves 4..7 = producers: gather+blend tap k+1 -> samp[(k+1)&1]. Same per-thread
//     sampling as v4 (16 loads / 32ch). No MFMA, no mid-chain vmcnt games.
//   - waves 0..3 = consumers: B-frags from fragment-contiguous wt2 (one coalesced
//     1KB wave-load per frag vs 16 scattered 64B rows) + 16 ds_read + 32 MFMA/kk.
//   - one barrier per tap; dbuf samp (34.8KB); launch_bounds(512,4) pins VGPR<=128
//     so 2 blocks/CU co-reside; s_setprio(1) around MFMA (role-split = the case
//     where it helps).
//   - keeps: XCD-local n=bid&7 (FETCH 41.6->6.5MB), cvt_pk_bf16, padded SROW.
// ws usage: xt = 8 MB at ws+0, wt2 = 288 KB at ws+8388608. Fully rewritten each launch.

#define H  64
#define W  64
#define CIN 128
#define COUT 128
#define NB 8
#define KK 9
#define SROW (CIN + 8)

typedef short bf16x8 __attribute__((ext_vector_type(8)));
typedef float f32x4  __attribute__((ext_vector_type(4)));

__device__ __forceinline__ unsigned short f2bf(float f) {
    unsigned u = __builtin_bit_cast(unsigned, f);
    u += 0x7FFFu + ((u >> 16) & 1u);          // round-nearest-even
    return (unsigned short)(u >> 16);
}
__device__ __forceinline__ unsigned cvt_pk_bf16(float lo, float hi) {
    unsigned r;
    asm("v_cvt_pk_bf16_f32 %0, %1, %2" : "=v"(r) : "v"(lo), "v"(hi));
    return r;                                  // low16 = bf16(lo), high16 = bf16(hi), RNE
}
__device__ __forceinline__ float lo_f(unsigned u) { return __builtin_bit_cast(float, u << 16); }
__device__ __forceinline__ float hi_f(unsigned u) { return __builtin_bit_cast(float, u & 0xFFFF0000u); }

// Merged prep: blocks [0, NB*H) transpose x (NCHW fp32 -> NHWC bf16), XCD-local (n = b&7);
// blocks [NB*H, NB*H+576): weight fp32 [co][c][kk] -> wt2 fragment-contiguous bf16:
//   wt2 flat idx = ((((kk*4 + c4)*2 + nt)*4 + ct)*64 + lm*4 + lq)*8 + e
//   where co = c4*32 + nt*16 + lm, ch = ct*32 + lq*8 + e.
// So one consumer B-frag load (nt,ct) is a contiguous 1KB wave read.
__global__ void prep_all(const float* __restrict__ x, const float* __restrict__ w,
                         unsigned short* __restrict__ xt, unsigned short* __restrict__ wt) {
    int b = blockIdx.x;
    int t = threadIdx.x;
    if (b >= NB * H) {                        // ---- weight part ----
        int idx = (b - NB * H) * 256 + t;
        if (idx < KK * COUT * CIN) {
            int e  = idx & 7;
            int lq = (idx >> 3) & 3;
            int lm = (idx >> 5) & 15;
            int ct = (idx >> 9) & 3;
            int nt = (idx >> 11) & 1;
            int c4 = (idx >> 12) & 3;
            int kk = idx >> 14;
            int co = (c4 << 5) + (nt << 4) + lm;
            int ch = (ct << 5) + (lq << 3) + e;
            wt[idx] = f2bf(w[(co * CIN + ch) * KK + kk]);
        }
        return;
    }
    // ---- x-transpose part: one (n,y) row per block; n = b&7 matches deform's XCD map ----
    __shared__ float tile[CIN][W + 4];
    int n = b & 7, y = b >> 3;
    const float* src = x + ((size_t)n * CIN * H + y) * W;
    #pragma unroll
    for (int it = 0; it < 8; ++it) {
        int idx = it * 256 + t;               // 0..2047 float4s
        int c  = idx >> 4;
        int x4 = (idx & 15) << 2;
        int xs = (x4 + ((c >> 5) << 4)) & 63; // rotate-swizzle per 32-ch group
        *(float4*)&tile[c][xs] = *(const float4*)(src + (size_t)c * H * W + x4);
    }
    __syncthreads();
    int xp = t >> 2;                          // x position 0..63
    int cbch = (t & 3) << 5;                  // channel base (32-ch chunk)
    int xr = (xp + ((cbch >> 5) << 4)) & 63;
    unsigned short* dst = xt + (((size_t)(n * H + y) * W + xp) * CIN + cbch);
    unsigned rr[16];
    #pragma unroll
    for (int i = 0; i < 16; ++i)
        rr[i] = cvt_pk_bf16(tile[cbch + 2 * i][xr], tile[cbch + 2 * i + 1][xr]);
    #pragma unroll
    for (int i = 0; i < 4; ++i)
        ((uint4*)dst)[i] = make_uint4(rr[4*i], rr[4*i+1], rr[4*i+2], rr[4*i+3]);
}

struct GatherCtx {
    const unsigned short *c00, *c01, *c10, *c11;
    float w00, w01, w10, w11;
};

__device__ __forceinline__ GatherCtx gather_setup(float dy, float dx, int ho, int wo, int kk,
                                                  const unsigned short* xbase) {
    GatherCtx g;
    float py = (float)(ho - 1 + kk / 3) + dy;
    float px = (float)(wo - 1 + kk % 3) + dx;
    float y0f = floorf(py), x0f = floorf(px);
    float wy1 = py - y0f, wx1 = px - x0f;
    float wy0 = 1.f - wy1, wx0 = 1.f - wx1;
    int y0 = (int)y0f, x0 = (int)x0f;
    int y1 = y0 + 1, x1 = x0 + 1;
    bool vy0 = (unsigned)y0 < (unsigned)H, vy1 = (unsigned)y1 < (unsigned)H;
    bool vx0 = (unsigned)x0 < (unsigned)W, vx1 = (unsigned)x1 < (unsigned)W;
    g.w00 = (vy0 && vx0) ? wy0 * wx0 : 0.f;
    g.w01 = (vy0 && vx1) ? wy0 * wx1 : 0.f;
    g.w10 = (vy1 && vx0) ? wy1 * wx0 : 0.f;
    g.w11 = (vy1 && vx1) ? wy1 * wx1 : 0.f;
    int yc0 = min(max(y0, 0), H - 1), yc1 = min(max(y1, 0), H - 1);
    int xc0 = min(max(x0, 0), W - 1), xc1 = min(max(x1, 0), W - 1);
    const unsigned short* r0 = xbase + (size_t)yc0 * W * CIN;
    const unsigned short* r1 = xbase + (size_t)yc1 * W * CIN;
    g.c00 = r0 + xc0 * CIN;  g.c01 = r0 + xc1 * CIN;
    g.c10 = r1 + xc0 * CIN;  g.c11 = r1 + xc1 * CIN;
    return g;
}

// 32 channels per thread: 4 x 16B per corner.
__device__ __forceinline__ void gather_issue(const GatherCtx& g, uint4* gv) {
    #pragma unroll
    for (int j = 0; j < 4; ++j) {
        gv[4*j+0] = *(const uint4*)(g.c00 + 8*j);
        gv[4*j+1] = *(const uint4*)(g.c01 + 8*j);
        gv[4*j+2] = *(const uint4*)(g.c10 + 8*j);
        gv[4*j+3] = *(const uint4*)(g.c11 + 8*j);
    }
}

__device__ __forceinline__ void gather_blend_store(const GatherCtx& g, const uint4* gv,
                                                   unsigned short* dst) {
    #pragma unroll
    for (int j = 0; j < 4; ++j) {
        const unsigned* a0 = (const unsigned*)&gv[4*j+0];
        const unsigned* a1 = (const unsigned*)&gv[4*j+1];
        const unsigned* a2 = (const unsigned*)&gv[4*j+2];
        const unsigned* a3 = (const unsigned*)&gv[4*j+3];
        unsigned rr[4];
        #pragma unroll
        for (int i = 0; i < 4; ++i) {
            float v0 = g.w00*lo_f(a0[i]) + g.w01*lo_f(a1[i]) + g.w10*lo_f(a2[i]) + g.w11*lo_f(a3[i]);
            float v1 = g.w00*hi_f(a0[i]) + g.w01*hi_f(a1[i]) + g.w10*hi_f(a2[i]) + g.w11*hi_f(a3[i]);
            rr[i] = cvt_pk_bf16(v0, v1);
        }
        *(uint4*)(dst + 8*j) = make_uint4(rr[0], rr[1], rr[2], rr[3]);
    }
}

// One block per (n, ho); n = bid&7 (XCD-local), ho = bid>>3. 512 threads = 8 waves.
// Waves 0..3 (consumers): wave wv covers 64 wo x couts wv*32..+31 (4 mt x 2 nt).
// Waves 4..7 (producers): thread t2=t-256 -> (p = t2>>2, cb = (t2&3)*32); build tap
// k+1 into samp[(k+1)&1] while consumers eat tap k from samp[k&1].
__global__ __launch_bounds__(512, 4) void deform_main(
        const float* __restrict__ offs, const unsigned short* __restrict__ xt,
        const unsigned short* __restrict__ wt, float* __restrict__ out) {
    // +8 bf16 pad per row -> row stride 272B (68 words == 4 mod 32)
    __shared__ __attribute__((aligned(16))) unsigned short samp[2][64][SROW];  // 34,816 B

    int b = blockIdx.x;
    int n = b & 7, ho = b >> 3;
    int t = threadIdx.x;
    int lane = t & 63, wv = t >> 6;
    bool producer = (wv >= 4);

    if (producer) {
        // ---------------- producer role ----------------
        int t2 = t - 256;
        int p  = t2 >> 2;                     // wo 0..63
        int cb = (t2 & 3) << 5;               // 32-channel chunk base
        const float* offbase = offs + (size_t)n * 2 * KK * H * W + (size_t)ho * W + p;
        const unsigned short* xbase = xt + (size_t)n * H * W * CIN + cb;

        // prologue: build tap 0 into samp[0]
        float dyA = offbase[0];
        float dxA = offbase[(size_t)H * W];
        {
            GatherCtx g = gather_setup(dyA, dxA, ho, p, 0, xbase);
            uint4 gv[16];
            gather_issue(g, gv);
            dyA = offbase[(size_t)2 * H * W];
            dxA = offbase[(size_t)3 * H * W];
            gather_blend_store(g, gv, &samp[0][p][cb]);
        }
        __syncthreads();
        for (int k = 0; k < KK; ++k) {
            if (k < KK - 1) {
                int tap = k + 1;
                GatherCtx g = gather_setup(dyA, dxA, ho, p, tap, xbase);
                uint4 gv[16];
                gather_issue(g, gv);
                if (k < KK - 2) {
                    dyA = offbase[(size_t)(2 * (tap + 1)) * H * W];
                    dxA = offbase[(size_t)(2 * (tap + 1) + 1) * H * W];
                }
                gather_blend_store(g, gv, &samp[tap & 1][p][cb]);
            }
            __syncthreads();
        }
        return;
    }

    // ---------------- consumer role ----------------
    int lm = lane & 15, lq = lane >> 4;
    int cobase = wv << 5;
    int slot = (lm << 2) + lq;                // fragment lane slot

    f32x4 acc[4][2];
    #pragma unroll
    for (int mt = 0; mt < 4; ++mt)
        #pragma unroll
        for (int nt = 0; nt < 2; ++nt) acc[mt][nt] = f32x4{0.f, 0.f, 0.f, 0.f};

    // fragment-contiguous weight base for this wave+lane (see prep_all layout comment)
    const unsigned short* wvbase = wt + ((size_t)wv << 12) + (slot << 3);

    __syncthreads();                          // wait for producers' tap 0
    for (int k = 0; k < KK; ++k) {
        // B-frags for tap k: 8 contiguous 1KB wave loads
        const unsigned short* wkb = wvbase + ((size_t)(k << 2) << 12);
        bf16x8 bW[2][4];
        #pragma unroll
        for (int nt = 0; nt < 2; ++nt)
            #pragma unroll
            for (int ct = 0; ct < 4; ++ct)
                bW[nt][ct] = *(const bf16x8*)(wkb + (((nt << 2) + ct) << 9));

        __builtin_amdgcn_s_setprio(1);
        #pragma unroll
        for (int ct = 0; ct < 4; ++ct) {
            bf16x8 a[4];
            #pragma unroll
            for (int mt = 0; mt < 4; ++mt)
                a[mt] = *(const bf16x8*)&samp[k & 1][lm + (mt << 4)][(ct << 5) + (lq << 3)];
            #pragma unroll
            for (int mt = 0; mt < 4; ++mt) {
                acc[mt][0] = __builtin_amdgcn_mfma_f32_16x16x32_bf16(a[mt], bW[0][ct], acc[mt][0], 0, 0, 0);
                acc[mt][1] = __builtin_amdgcn_mfma_f32_16x16x32_bf16(a[mt], bW[1][ct], acc[mt][1], 0, 0, 0);
            }
        }
        __builtin_amdgcn_s_setprio(0);
        __syncthreads();
    }

    // epilogue: D[m = mt*16 + lq*4 + j][n = lm] -> out[n][co][ho][wo], float4 over wo
    #pragma unroll
    for (int mt = 0; mt < 4; ++mt) {
        int wob = (mt << 4) + (lq << 2);
        #pragma unroll
        for (int nt = 0; nt < 2; ++nt) {
            int co = cobase + (nt << 4) + lm;
            *(f32x4*)(out + (((size_t)(n * COUT + co) * H + ho) * W + wob)) = acc[mt][nt];
        }
    }
}

extern "C" void kernel_launch(void* const* d_in, const int* in_sizes, int n_in,
                              void* d_out, int out_size, void* d_ws, size_t ws_size,
                              hipStream_t stream) {
    const float* x      = (const float*)d_in[0];   // (8,128,64,64)
    const float* offset = (const float*)d_in[1];   // (8,18,64,64)
    const float* weight = (const float*)d_in[2];   // (128,128,3,3)
    float* out = (float*)d_out;

    unsigned short* xt = (unsigned short*)d_ws;                                  // 8 MB
    unsigned short* wt = (unsigned short*)((char*)d_ws + (size_t)NB*H*W*CIN*2);  // 288 KB

    int wblocks = (KK * COUT * CIN + 255) / 256;   // 576
    hipLaunchKernelGGL(prep_all, dim3(NB * H + wblocks), dim3(256), 0, stream,
                       x, weight, xt, wt);
    hipLaunchKernelGGL(deform_main, dim3(NB * H), dim3(512), 0, stream,
                       offset, xt, wt, out);
}

// Round 7
// 108.205 us; speedup vs baseline: 1.1145x; 1.0261x over previous
//
#include <hip/hip_runtime.h>

// Deformable conv (K=3, stride=1, pad=1, dil=1), N=8, Cin=Cout=128, H=W=64.
// v8: decoupled producer/consumer (NO per-tap __syncthreads).
//   v7 kept the per-tap barrier -> 8 waves lockstep to the slowest chain each tap
//   (~10.9K cyc/tap vs ~1.5K cyc of actual pipe work). v8:
//   - samp TRIPLE-buffered (3 x 17.4KB); LDS flag counters rdy[9]/dn[9] replace
//     barriers. Producers signal rdy[tap] after lgkmcnt(0); consumers spin
//     (s_sleep) until rdy[tap]==4; consumers signal dn[tap]; producers only wait
//     dn[tap-3] before reusing a buffer -> up to 3 taps in flight, waves slip freely.
//   - consumers prefetch B-frags via unsinkable asm loads BEFORE the spin; the
//     spin absorbs the weight L2 latency; vmcnt(0)+sched_barrier before MFMA use.
//   - producers blend into regs BEFORE the buffer-free wait; only ds_writes after.
//   - launch_bounds(512,4) pins VGPR<=128 -> 2 blocks/CU (LDS 104.6KB/CU).
//   - keeps: XCD-local n=bid&7, fragment-contiguous wt2, cvt_pk_bf16, padded SROW,
//     s_setprio around MFMA.
// ws usage: xt = 8 MB at ws+0, wt2 = 288 KB at ws+8388608. Fully rewritten each launch.

#define H  64
#define W  64
#define CIN 128
#define COUT 128
#define NB 8
#define KK 9
#define SROW (CIN + 8)

typedef short bf16x8 __attribute__((ext_vector_type(8)));
typedef float f32x4  __attribute__((ext_vector_type(4)));

// unsinkable 16B global load into explicit VGPRs
#define GLOADX4(dst, ptr) \
    asm volatile("global_load_dwordx4 %0, %1, off" : "=v"(dst) : "v"(ptr))

__device__ __forceinline__ unsigned short f2bf(float f) {
    unsigned u = __builtin_bit_cast(unsigned, f);
    u += 0x7FFFu + ((u >> 16) & 1u);          // round-nearest-even
    return (unsigned short)(u >> 16);
}
__device__ __forceinline__ unsigned cvt_pk_bf16(float lo, float hi) {
    unsigned r;
    asm("v_cvt_pk_bf16_f32 %0, %1, %2" : "=v"(r) : "v"(lo), "v"(hi));
    return r;                                  // low16 = bf16(lo), high16 = bf16(hi), RNE
}
__device__ __forceinline__ float lo_f(unsigned u) { return __builtin_bit_cast(float, u << 16); }
__device__ __forceinline__ float hi_f(unsigned u) { return __builtin_bit_cast(float, u & 0xFFFF0000u); }

// Merged prep: blocks [0, NB*H) transpose x (NCHW fp32 -> NHWC bf16), XCD-local (n = b&7);
// blocks [NB*H, NB*H+576): weight fp32 [co][c][kk] -> wt2 fragment-contiguous bf16:
//   wt2 flat idx = ((((kk*4 + c4)*2 + nt)*4 + ct)*64 + lm*4 + lq)*8 + e
//   where co = c4*32 + nt*16 + lm, ch = ct*32 + lq*8 + e.
__global__ void prep_all(const float* __restrict__ x, const float* __restrict__ w,
                         unsigned short* __restrict__ xt, unsigned short* __restrict__ wt) {
    int b = blockIdx.x;
    int t = threadIdx.x;
    if (b >= NB * H) {                        // ---- weight part ----
        int idx = (b - NB * H) * 256 + t;
        if (idx < KK * COUT * CIN) {
            int e  = idx & 7;
            int lq = (idx >> 3) & 3;
            int lm = (idx >> 5) & 15;
            int ct = (idx >> 9) & 3;
            int nt = (idx >> 11) & 1;
            int c4 = (idx >> 12) & 3;
            int kk = idx >> 14;
            int co = (c4 << 5) + (nt << 4) + lm;
            int ch = (ct << 5) + (lq << 3) + e;
            wt[idx] = f2bf(w[(co * CIN + ch) * KK + kk]);
        }
        return;
    }
    // ---- x-transpose part: one (n,y) row per block; n = b&7 matches deform's XCD map ----
    __shared__ float tile[CIN][W + 4];
    int n = b & 7, y = b >> 3;
    const float* src = x + ((size_t)n * CIN * H + y) * W;
    #pragma unroll
    for (int it = 0; it < 8; ++it) {
        int idx = it * 256 + t;               // 0..2047 float4s
        int c  = idx >> 4;
        int x4 = (idx & 15) << 2;
        int xs = (x4 + ((c >> 5) << 4)) & 63; // rotate-swizzle per 32-ch group
        *(float4*)&tile[c][xs] = *(const float4*)(src + (size_t)c * H * W + x4);
    }
    __syncthreads();
    int xp = t >> 2;                          // x position 0..63
    int cbch = (t & 3) << 5;                  // channel base (32-ch chunk)
    int xr = (xp + ((cbch >> 5) << 4)) & 63;
    unsigned short* dst = xt + (((size_t)(n * H + y) * W + xp) * CIN + cbch);
    unsigned rr[16];
    #pragma unroll
    for (int i = 0; i < 16; ++i)
        rr[i] = cvt_pk_bf16(tile[cbch + 2 * i][xr], tile[cbch + 2 * i + 1][xr]);
    #pragma unroll
    for (int i = 0; i < 4; ++i)
        ((uint4*)dst)[i] = make_uint4(rr[4*i], rr[4*i+1], rr[4*i+2], rr[4*i+3]);
}

struct GatherCtx {
    const unsigned short *c00, *c01, *c10, *c11;
    float w00, w01, w10, w11;
};

__device__ __forceinline__ GatherCtx gather_setup(float dy, float dx, int ho, int wo, int kk,
                                                  const unsigned short* xbase) {
    GatherCtx g;
    float py = (float)(ho - 1 + kk / 3) + dy;
    float px = (float)(wo - 1 + kk % 3) + dx;
    float y0f = floorf(py), x0f = floorf(px);
    float wy1 = py - y0f, wx1 = px - x0f;
    float wy0 = 1.f - wy1, wx0 = 1.f - wx1;
    int y0 = (int)y0f, x0 = (int)x0f;
    int y1 = y0 + 1, x1 = x0 + 1;
    bool vy0 = (unsigned)y0 < (unsigned)H, vy1 = (unsigned)y1 < (unsigned)H;
    bool vx0 = (unsigned)x0 < (unsigned)W, vx1 = (unsigned)x1 < (unsigned)W;
    g.w00 = (vy0 && vx0) ? wy0 * wx0 : 0.f;
    g.w01 = (vy0 && vx1) ? wy0 * wx1 : 0.f;
    g.w10 = (vy1 && vx0) ? wy1 * wx0 : 0.f;
    g.w11 = (vy1 && vx1) ? wy1 * wx1 : 0.f;
    int yc0 = min(max(y0, 0), H - 1), yc1 = min(max(y1, 0), H - 1);
    int xc0 = min(max(x0, 0), W - 1), xc1 = min(max(x1, 0), W - 1);
    const unsigned short* r0 = xbase + (size_t)yc0 * W * CIN;
    const unsigned short* r1 = xbase + (size_t)yc1 * W * CIN;
    g.c00 = r0 + xc0 * CIN;  g.c01 = r0 + xc1 * CIN;
    g.c10 = r1 + xc0 * CIN;  g.c11 = r1 + xc1 * CIN;
    return g;
}

// 32 channels per thread: 4 x 16B per corner.
__device__ __forceinline__ void gather_issue(const GatherCtx& g, uint4* gv) {
    #pragma unroll
    for (int j = 0; j < 4; ++j) {
        gv[4*j+0] = *(const uint4*)(g.c00 + 8*j);
        gv[4*j+1] = *(const uint4*)(g.c01 + 8*j);
        gv[4*j+2] = *(const uint4*)(g.c10 + 8*j);
        gv[4*j+3] = *(const uint4*)(g.c11 + 8*j);
    }
}

// blend into 16 packed words (registers only; stores happen after the buffer-free wait)
__device__ __forceinline__ void gather_blend(const GatherCtx& g, const uint4* gv, unsigned* rr) {
    #pragma unroll
    for (int j = 0; j < 4; ++j) {
        const unsigned* a0 = (const unsigned*)&gv[4*j+0];
        const unsigned* a1 = (const unsigned*)&gv[4*j+1];
        const unsigned* a2 = (const unsigned*)&gv[4*j+2];
        const unsigned* a3 = (const unsigned*)&gv[4*j+3];
        #pragma unroll
        for (int i = 0; i < 4; ++i) {
            float v0 = g.w00*lo_f(a0[i]) + g.w01*lo_f(a1[i]) + g.w10*lo_f(a2[i]) + g.w11*lo_f(a3[i]);
            float v1 = g.w00*hi_f(a0[i]) + g.w01*hi_f(a1[i]) + g.w10*hi_f(a2[i]) + g.w11*hi_f(a3[i]);
            rr[4*j+i] = cvt_pk_bf16(v0, v1);
        }
    }
}

// One block per (n, ho); n = bid&7 (XCD-local), ho = bid>>3. 512 threads = 8 waves.
// Waves 0..3 consumers (wave wv: 64 wo x couts wv*32..+31); waves 4..7 producers.
__global__ __launch_bounds__(512, 4) void deform_main(
        const float* __restrict__ offs, const unsigned short* __restrict__ xt,
        const unsigned short* __restrict__ wt, float* __restrict__ out) {
    __shared__ __attribute__((aligned(16))) unsigned short samp[3][64][SROW];  // 52,224 B
    __shared__ int rdy[KK];   // producer-wave completion count per tap
    __shared__ int dn[KK];    // consumer-wave completion count per tap

    int b = blockIdx.x;
    int n = b & 7, ho = b >> 3;
    int t = threadIdx.x;
    int lane = t & 63, wv = t >> 6;

    if (t < KK) { rdy[t] = 0; dn[t] = 0; }
    __syncthreads();                          // flags visible to all waves (only barrier)

    if (wv >= 4) {
        // ---------------- producer role ----------------
        int t2 = t - 256;
        int p  = t2 >> 2;                     // wo 0..63
        int cb = (t2 & 3) << 5;               // 32-channel chunk base
        const float* offbase = offs + (size_t)n * 2 * KK * H * W + (size_t)ho * W + p;
        const unsigned short* xbase = xt + (size_t)n * H * W * CIN + cb;

        float dyA = offbase[0];
        float dxA = offbase[(size_t)H * W];
        #pragma unroll
        for (int tap = 0; tap < KK; ++tap) {
            GatherCtx g = gather_setup(dyA, dxA, ho, p, tap, xbase);
            uint4 gv[16];
            gather_issue(g, gv);
            if (tap < KK - 1) {
                dyA = offbase[(size_t)(2 * (tap + 1)) * H * W];
                dxA = offbase[(size_t)(2 * (tap + 1) + 1) * H * W];
            }
            unsigned rr[16];
            gather_blend(g, gv, rr);
            if (tap >= 3) {                   // buffer tap%3 reused: wait consumers done tap-3
                while (__hip_atomic_load(&dn[tap - 3], __ATOMIC_ACQUIRE,
                                         __HIP_MEMORY_SCOPE_WORKGROUP) < 4)
                    __builtin_amdgcn_s_sleep(2);
            }
            unsigned short* dst = &samp[tap % 3][p][cb];
            #pragma unroll
            for (int i = 0; i < 4; ++i)
                *(uint4*)(dst + 8 * i) = make_uint4(rr[4*i], rr[4*i+1], rr[4*i+2], rr[4*i+3]);
            asm volatile("s_waitcnt lgkmcnt(0)" ::: "memory");   // data before flag
            if (lane == 0) atomicAdd(&rdy[tap], 1);
        }
        return;
    }

    // ---------------- consumer role ----------------
    int lm = lane & 15, lq = lane >> 4;
    int cobase = wv << 5;
    int slot = (lm << 2) + lq;

    f32x4 acc[4][2];
    #pragma unroll
    for (int mt = 0; mt < 4; ++mt)
        #pragma unroll
        for (int nt = 0; nt < 2; ++nt) acc[mt][nt] = f32x4{0.f, 0.f, 0.f, 0.f};

    const unsigned short* wvbase = wt + ((size_t)wv << 12) + (slot << 3);

    #pragma unroll
    for (int tap = 0; tap < KK; ++tap) {
        // B-frags for this tap: issued (unsinkable) BEFORE the spin -> latency absorbed
        const unsigned short* wkb = wvbase + ((size_t)(tap << 2) << 12);
        bf16x8 bW[2][4];
        #pragma unroll
        for (int nt = 0; nt < 2; ++nt)
            #pragma unroll
            for (int ct = 0; ct < 4; ++ct)
                GLOADX4(bW[nt][ct], (wkb + (((nt << 2) + ct) << 9)));

        while (__hip_atomic_load(&rdy[tap], __ATOMIC_ACQUIRE,
                                 __HIP_MEMORY_SCOPE_WORKGROUP) < 4)
            __builtin_amdgcn_s_sleep(2);
        asm volatile("s_waitcnt vmcnt(0)" ::: "memory");   // bW landed
        __builtin_amdgcn_sched_barrier(0);

        __builtin_amdgcn_s_setprio(1);
        #pragma unroll
        for (int ct = 0; ct < 4; ++ct) {
            bf16x8 a[4];
            #pragma unroll
            for (int mt = 0; mt < 4; ++mt)
                a[mt] = *(const bf16x8*)&samp[tap % 3][lm + (mt << 4)][(ct << 5) + (lq << 3)];
            #pragma unroll
            for (int mt = 0; mt < 4; ++mt) {
                acc[mt][0] = __builtin_amdgcn_mfma_f32_16x16x32_bf16(a[mt], bW[0][ct], acc[mt][0], 0, 0, 0);
                acc[mt][1] = __builtin_amdgcn_mfma_f32_16x16x32_bf16(a[mt], bW[1][ct], acc[mt][1], 0, 0, 0);
            }
        }
        __builtin_amdgcn_s_setprio(0);
        asm volatile("s_waitcnt lgkmcnt(0)" ::: "memory");  // samp reads done before signal
        __builtin_amdgcn_sched_barrier(0);
        if (lane == 0) atomicAdd(&dn[tap], 1);
    }

    // epilogue: D[m = mt*16 + lq*4 + j][n = lm] -> out[n][co][ho][wo], float4 over wo
    #pragma unroll
    for (int mt = 0; mt < 4; ++mt) {
        int wob = (mt << 4) + (lq << 2);
        #pragma unroll
        for (int nt = 0; nt < 2; ++nt) {
            int co = cobase + (nt << 4) + lm;
            *(f32x4*)(out + (((size_t)(n * COUT + co) * H + ho) * W + wob)) = acc[mt][nt];
        }
    }
}

extern "C" void kernel_launch(void* const* d_in, const int* in_sizes, int n_in,
                              void* d_out, int out_size, void* d_ws, size_t ws_size,
                              hipStream_t stream) {
    const float* x      = (const float*)d_in[0];   // (8,128,64,64)
    const float* offset = (const float*)d_in[1];   // (8,18,64,64)
    const float* weight = (const float*)d_in[2];   // (128,128,3,3)
    float* out = (float*)d_out;

    unsigned short* xt = (unsigned short*)d_ws;                                  // 8 MB
    unsigned short* wt = (unsigned short*)((char*)d_ws + (size_t)NB*H*W*CIN*2);  // 288 KB

    int wblocks = (KK * COUT * CIN + 255) / 256;   // 576
    hipLaunchKernelGGL(prep_all, dim3(NB * H + wblocks), dim3(256), 0, stream,
                       x, weight, xt, wt);
    hipLaunchKernelGGL(deform_main, dim3(NB * H), dim3(512), 0, stream,
                       offset, xt, wt, out);
}